// Round 12
// baseline (10441.285 us; speedup 1.0000x reference)
//
#include <hip/hip_runtime.h>

#define TT 32768
#define BB 32

typedef _Float16 half2_t __attribute__((ext_vector_type(2)));
union H2U { half2_t h2; unsigned u; _Float16 h[2]; };

static __device__ __forceinline__ unsigned packh2(float a, float b) {
    H2U t; t.h[0] = (_Float16)a; t.h[1] = (_Float16)b; return t.u;
}
static __device__ __forceinline__ float fdot2u(unsigned wu, unsigned hu, float acc) {
    H2U w, h; w.u = wu; h.u = hu;
    return __builtin_amdgcn_fdot2(w.h2, h.h2, acc, false);
}
static __device__ __forceinline__ float rlanef(float v, int lane) {
    return __uint_as_float((unsigned)__builtin_amdgcn_readlane((int)__float_as_uint(v), lane));
}
template <int CTRL>
static __device__ __forceinline__ float dppf(float v) {
    return __uint_as_float((unsigned)__builtin_amdgcn_mov_dpp(
        (int)__float_as_uint(v), CTRL, 0xF, 0xF, true));
}
static __device__ __forceinline__ float exp2_raw(float x) {
    float r; asm("v_exp_f32 %0, %1" : "=v"(r) : "v"(x)); return r;
}

// 8 waves per batch element, split-K (round-10/11 topology), final trims:
// - h-reads issue FIRST after the barrier; xv readlane + acc inits fill the
//   ~120cy ds_read latency window.
// - step 63 drains lgkmcnt(0) so its barrier also covers the window flush
//   (extra flush barrier deleted).
// - x prefetch at mid-window (sw==30), away from the flush boundary.
// - 8 accumulator chains (shorter dot dependency tail).
__global__ __launch_bounds__(512, 2) void lstm_fused(
    const float* __restrict__ x,      // [T,B]
    const float* __restrict__ W_ih,   // [256]
    const float* __restrict__ W_hh,   // [256,64]  rows: i,f,g,o
    const float* __restrict__ b_ih,   // [256]
    const float* __restrict__ b_hh,   // [256]
    const float* __restrict__ W_out,  // [64]
    const float* __restrict__ b_out,  // [1]
    float* __restrict__ out)          // [T,B]
{
    const int b   = blockIdx.x;
    const int tid = threadIdx.x;
    const int w   = tid >> 6;         // wave id (0..7)
    const int l   = tid & 63;         // lane
    const int g   = l & 3;            // gate (0=i,1=f,2=g,3=o)
    const int kh  = (l >> 2) & 1;     // k-half
    const int n   = 8 * w + (l >> 3); // h index this lane serves

    __shared__ _Float16 hbuf[2][64];  // fp16 h, double-buffered
    __shared__ float    pbuf[64][65]; // output partials [step][h-index], padded

    const float L2E = 1.4426950408889634f;
    const float si  = (g == 2) ? (-2.f * L2E) : (-L2E);
    const float nm_out = (g == 0) ? (-2.f * L2E) : ((g == 2) ? 2.f : 1.f);
    const float na     = (g == 2) ? -1.f : 0.f;

    unsigned wgp[16];
    #pragma unroll
    for (int j = 0; j < 8; ++j) {
        const float4 v = *reinterpret_cast<const float4*>(
            &W_hh[(g * 64 + n) * 64 + 32 * kh + 4 * j]);
        wgp[2 * j]     = packh2(si * v.x, si * v.y);
        wgp[2 * j + 1] = packh2(si * v.z, si * v.w);
    }
    const float wih  = (kh == 0) ? si * W_ih[g * 64 + n] : 0.f;
    const float bias = (kh == 0) ? si * (b_ih[g * 64 + n] + b_hh[g * 64 + n]) : 0.f;
    const float wo_n = W_out[n];
    const float bo   = b_out[0];
    const bool  prod = ((l & 7) == 0);

    float c = 0.f;                    // scaled domain: c' = -2log2e * c_true

    if (tid < 64) ((unsigned*)hbuf)[tid] = 0u;
    float xwin  = x[(size_t)l * BB + b];
    float xnext = 0.f;
    __syncthreads();

    const unsigned* hbr0 = reinterpret_cast<const unsigned*>(&hbuf[0][0]) + 16 * kh;
    const unsigned* hbr1 = reinterpret_cast<const unsigned*>(&hbuf[1][0]) + 16 * kh;

// LGKM: 1 on ordinary steps (h-write committed, pbuf may lag);
//       0 on step 63 (drain both -> barrier doubles as flush barrier).
#define LSTM_STEP(S, HBR, WRSLOT, LGKM)                                        \
    do {                                                                       \
        /* issue h-reads first; fill latency with xv + acc inits */            \
        const uint4 h0 = *reinterpret_cast<const uint4*>((HBR));               \
        const uint4 h1 = *reinterpret_cast<const uint4*>((HBR) + 4);           \
        const uint4 h2 = *reinterpret_cast<const uint4*>((HBR) + 8);           \
        const uint4 h3 = *reinterpret_cast<const uint4*>((HBR) + 12);          \
        const float xv = rlanef(xwin, (S));                                    \
        float a0 = fmaf(xv, wih, bias);                                        \
        float a1 = 0.f, a2 = 0.f, a3 = 0.f;                                    \
        float a4 = 0.f, a5 = 0.f, a6 = 0.f, a7 = 0.f;                          \
        a0 = fdot2u(wgp[0],  h0.x, a0); a1 = fdot2u(wgp[1],  h0.y, a1);        \
        a2 = fdot2u(wgp[2],  h0.z, a2); a3 = fdot2u(wgp[3],  h0.w, a3);        \
        a4 = fdot2u(wgp[4],  h1.x, a4); a5 = fdot2u(wgp[5],  h1.y, a5);        \
        a6 = fdot2u(wgp[6],  h1.z, a6); a7 = fdot2u(wgp[7],  h1.w, a7);        \
        a0 = fdot2u(wgp[8],  h2.x, a0); a1 = fdot2u(wgp[9],  h2.y, a1);        \
        a2 = fdot2u(wgp[10], h2.z, a2); a3 = fdot2u(wgp[11], h2.w, a3);        \
        a4 = fdot2u(wgp[12], h3.x, a4); a5 = fdot2u(wgp[13], h3.y, a5);        \
        a6 = fdot2u(wgp[14], h3.z, a6); a7 = fdot2u(wgp[15], h3.w, a7);        \
        const float ph  = ((a0 + a1) + (a2 + a3)) + ((a4 + a5) + (a6 + a7));   \
        const float pre = ph + dppf<0x104>(ph);                                \
        const float gv  = fmaf(__builtin_amdgcn_rcpf(1.f + exp2_raw(pre)),     \
                               nm_out, na);                                    \
        const float fv = dppf<0x55>(gv);                                       \
        const float gg = dppf<0xAA>(gv);                                       \
        const float ov = dppf<0xFF>(gv);                                       \
        c = fmaf(fv, c, gv * gg);                                              \
        const float rc = __builtin_amdgcn_rcpf(1.f + exp2_raw(c));             \
        const float hn = fmaf(2.f * ov, rc, -ov);                              \
        if (prod) {                                                            \
            hbuf[(WRSLOT)][n] = (_Float16)hn;                                  \
            asm volatile("" ::: "memory");                                     \
            pbuf[(S)][n] = hn * wo_n;                                          \
        }                                                                      \
        asm volatile("s_waitcnt lgkmcnt(" #LGKM ")" ::: "memory");             \
        __builtin_amdgcn_s_barrier();                                          \
        asm volatile("" ::: "memory");                                         \
    } while (0)

    #pragma unroll 1
    for (int t2 = 0; t2 < TT; t2 += 2) {
        const int sw = t2 & 63;

        if (sw == 30) {               // prefetch next x window, mid-window
            int idx = (t2 - 30) + 64 + l; if (idx > TT - 1) idx = TT - 1;
            xnext = x[(size_t)idx * BB + b];
        }

        if (sw != 62) {
            LSTM_STEP(sw,     hbr0, 1, 1);
            LSTM_STEP(sw + 1, hbr1, 0, 1);
        } else {
            LSTM_STEP(62, hbr0, 1, 1);
            LSTM_STEP(63, hbr1, 0, 0);   // drain-all; barrier covers flush
            // window flush (all 8 waves, 8 rows each); safe vs next window's
            // pbuf writes: those happen >200cy into step 0, flush reads ~60cy.
            const int r  = 8 * w + (l >> 3);
            const int c8 = (l & 7) * 8;
            const float4 v0 = *reinterpret_cast<const float4*>(&pbuf[r][c8]);
            const float4 v1 = *reinterpret_cast<const float4*>(&pbuf[r][c8 + 4]);
            float sum = ((v0.x + v0.y) + (v0.z + v0.w)) +
                        ((v1.x + v1.y) + (v1.z + v1.w));
            sum += dppf<0xB1>(sum);
            sum += dppf<0x4E>(sum);
            sum += dppf<0x104>(sum);
            const float xr = __uint_as_float((unsigned)__builtin_amdgcn_ds_bpermute(
                4 * r, (int)__float_as_uint(xwin)));
            if (prod) {
                const int tt = (t2 & ~63) + r;
                out[(size_t)tt * BB + b] = sum + bo + xr;
            }
            xwin = xnext;
        }
    }
#undef LSTM_STEP
}

extern "C" void kernel_launch(void* const* d_in, const int* in_sizes, int n_in,
                              void* d_out, int out_size, void* d_ws, size_t ws_size,
                              hipStream_t stream) {
    (void)in_sizes; (void)n_in; (void)d_ws; (void)ws_size; (void)out_size;
    const float* x    = (const float*)d_in[0];
    const float* wih  = (const float*)d_in[1];
    const float* whh  = (const float*)d_in[2];
    const float* bih  = (const float*)d_in[3];
    const float* bhh  = (const float*)d_in[4];
    const float* wout = (const float*)d_in[5];
    const float* bout = (const float*)d_in[6];
    hipLaunchKernelGGL(lstm_fused, dim3(BB), dim3(512), 0, stream,
                       x, wih, whh, bih, bhh, wout, bout, (float*)d_out);
}

// Round 13
// 9114.365 us; speedup vs baseline: 1.1456x; 1.1456x over previous
//
#include <hip/hip_runtime.h>

#define TT 32768
#define BB 32

typedef _Float16 half2_t __attribute__((ext_vector_type(2)));
union H2U { half2_t h2; unsigned u; _Float16 h[2]; };

static __device__ __forceinline__ unsigned packh2(float a, float b) {
    H2U t; t.h[0] = (_Float16)a; t.h[1] = (_Float16)b; return t.u;
}
static __device__ __forceinline__ float fdot2u(unsigned wu, unsigned hu, float acc) {
    H2U w, h; w.u = wu; h.u = hu;
    return __builtin_amdgcn_fdot2(w.h2, h.h2, acc, false);
}
static __device__ __forceinline__ float rlanef(float v, int lane) {
    return __uint_as_float((unsigned)__builtin_amdgcn_readlane((int)__float_as_uint(v), lane));
}
template <int CTRL>
static __device__ __forceinline__ float dppf(float v) {
    return __uint_as_float((unsigned)__builtin_amdgcn_mov_dpp(
        (int)__float_as_uint(v), CTRL, 0xF, 0xF, true));
}
static __device__ __forceinline__ float exp2_raw(float x) {
    float r; asm("v_exp_f32 %0, %1" : "=v"(r) : "v"(x)); return r;
}

// ROUND-11 REVERT (best measured: 9.12 ms). Round 12's manual h-read-first
// reorder + 8-chain accumulators REGRESSED to 10.44 ms — the compiler's own
// interleave of ds_read_b128 with the dot chain (fine lgkmcnt waits) beats a
// hand-forced reads-then-compute order. Keep source order that lets the
// scheduler hide LDS latency itself.
//
// 8 waves per batch element, split-K. Wave w owns h-indices [8w,8w+8);
// lane l = 8m + 4*kh + g computes gate g of index n=8w+m over k-half kh.
// - unroll x2 with rp-specialized bodies: LDS addresses loop-invariant.
// - counted drain lgkmcnt(1): hbuf write (emitted first, same-wave DS
//   retires in order) committed at the barrier; pbuf partial may lag and is
//   drained by the flush's own lgkmcnt(0)+barrier (1 per 64 steps).
// - exp prescales folded into weights; c kept in scaled domain c'=-2log2e*c.
__global__ __launch_bounds__(512, 2) void lstm_fused(
    const float* __restrict__ x,      // [T,B]
    const float* __restrict__ W_ih,   // [256]
    const float* __restrict__ W_hh,   // [256,64]  rows: i,f,g,o
    const float* __restrict__ b_ih,   // [256]
    const float* __restrict__ b_hh,   // [256]
    const float* __restrict__ W_out,  // [64]
    const float* __restrict__ b_out,  // [1]
    float* __restrict__ out)          // [T,B]
{
    const int b   = blockIdx.x;
    const int tid = threadIdx.x;
    const int w   = tid >> 6;         // wave id (0..7)
    const int l   = tid & 63;         // lane
    const int g   = l & 3;            // gate (0=i,1=f,2=g,3=o)
    const int kh  = (l >> 2) & 1;     // k-half
    const int n   = 8 * w + (l >> 3); // h index this lane serves

    __shared__ _Float16 hbuf[2][64];  // fp16 h, double-buffered
    __shared__ float    pbuf[64][65]; // output partials [step][h-index], padded

    const float L2E = 1.4426950408889634f;
    const float si  = (g == 2) ? (-2.f * L2E) : (-L2E);
    const float nm_out = (g == 0) ? (-2.f * L2E) : ((g == 2) ? 2.f : 1.f);
    const float na     = (g == 2) ? -1.f : 0.f;

    unsigned wgp[16];
    #pragma unroll
    for (int j = 0; j < 8; ++j) {
        const float4 v = *reinterpret_cast<const float4*>(
            &W_hh[(g * 64 + n) * 64 + 32 * kh + 4 * j]);
        wgp[2 * j]     = packh2(si * v.x, si * v.y);
        wgp[2 * j + 1] = packh2(si * v.z, si * v.w);
    }
    const float wih  = (kh == 0) ? si * W_ih[g * 64 + n] : 0.f;
    const float bias = (kh == 0) ? si * (b_ih[g * 64 + n] + b_hh[g * 64 + n]) : 0.f;
    const float wo_n = W_out[n];
    const float bo   = b_out[0];
    const bool  prod = ((l & 7) == 0);

    float c = 0.f;                    // scaled domain: c' = -2log2e * c_true

    if (tid < 64) ((unsigned*)hbuf)[tid] = 0u;
    float xwin  = x[(size_t)l * BB + b];
    float xnext = 0.f;
    __syncthreads();

    // loop-invariant LDS read bases (one VGPR each; 16B-imm-offset reads)
    const unsigned* hbr0 = reinterpret_cast<const unsigned*>(&hbuf[0][0]) + 16 * kh;
    const unsigned* hbr1 = reinterpret_cast<const unsigned*>(&hbuf[1][0]) + 16 * kh;

#define LSTM_STEP(S, HBR, WRSLOT)                                              \
    do {                                                                       \
        const float xv = rlanef(xwin, (S));                                    \
        float a0 = fmaf(xv, wih, bias), a1 = 0.f, a2 = 0.f, a3 = 0.f;          \
        const uint4 h0 = *reinterpret_cast<const uint4*>((HBR));               \
        const uint4 h1 = *reinterpret_cast<const uint4*>((HBR) + 4);           \
        const uint4 h2 = *reinterpret_cast<const uint4*>((HBR) + 8);           \
        const uint4 h3 = *reinterpret_cast<const uint4*>((HBR) + 12);          \
        a0 = fdot2u(wgp[0],  h0.x, a0); a1 = fdot2u(wgp[1],  h0.y, a1);        \
        a2 = fdot2u(wgp[2],  h0.z, a2); a3 = fdot2u(wgp[3],  h0.w, a3);        \
        a0 = fdot2u(wgp[4],  h1.x, a0); a1 = fdot2u(wgp[5],  h1.y, a1);        \
        a2 = fdot2u(wgp[6],  h1.z, a2); a3 = fdot2u(wgp[7],  h1.w, a3);        \
        a0 = fdot2u(wgp[8],  h2.x, a0); a1 = fdot2u(wgp[9],  h2.y, a1);        \
        a2 = fdot2u(wgp[10], h2.z, a2); a3 = fdot2u(wgp[11], h2.w, a3);        \
        a0 = fdot2u(wgp[12], h3.x, a0); a1 = fdot2u(wgp[13], h3.y, a1);        \
        a2 = fdot2u(wgp[14], h3.z, a2); a3 = fdot2u(wgp[15], h3.w, a3);        \
        const float ph  = (a0 + a1) + (a2 + a3);                               \
        const float pre = ph + dppf<0x104>(ph);                                \
        const float gv  = fmaf(__builtin_amdgcn_rcpf(1.f + exp2_raw(pre)),     \
                               nm_out, na);                                    \
        const float fv = dppf<0x55>(gv);                                       \
        const float gg = dppf<0xAA>(gv);                                       \
        const float ov = dppf<0xFF>(gv);                                       \
        c = fmaf(fv, c, gv * gg);                                              \
        const float rc = __builtin_amdgcn_rcpf(1.f + exp2_raw(c));             \
        const float hn = fmaf(2.f * ov, rc, -ov);                              \
        if (prod) {                                                            \
            hbuf[(WRSLOT)][n] = (_Float16)hn;                                  \
            asm volatile("" ::: "memory");                                     \
            pbuf[(S)][n] = hn * wo_n;                                          \
        }                                                                      \
        asm volatile("s_waitcnt lgkmcnt(1)" ::: "memory");                     \
        __builtin_amdgcn_s_barrier();                                          \
        asm volatile("" ::: "memory");                                         \
    } while (0)

    #pragma unroll 1
    for (int t2 = 0; t2 < TT; t2 += 2) {
        const int sw = t2 & 63;

        if (sw == 0) {                // prefetch next x window, ~62 steps deep
            int idx = t2 + 64 + l; if (idx > TT - 1) idx = TT - 1;
            xnext = x[(size_t)idx * BB + b];
        }

        LSTM_STEP(sw,     hbr0, 1);   // even step: read buf0, write buf1
        LSTM_STEP(sw + 1, hbr1, 0);   // odd  step: read buf1, write buf0

        if (sw == 62) {               // window flush (after step s=63's barrier)
            asm volatile("s_waitcnt lgkmcnt(0)" ::: "memory");
            __builtin_amdgcn_s_barrier();
            asm volatile("" ::: "memory");
            const int r  = 8 * w + (l >> 3);
            const int c8 = (l & 7) * 8;
            const float4 v0 = *reinterpret_cast<const float4*>(&pbuf[r][c8]);
            const float4 v1 = *reinterpret_cast<const float4*>(&pbuf[r][c8 + 4]);
            float sum = ((v0.x + v0.y) + (v0.z + v0.w)) +
                        ((v1.x + v1.y) + (v1.z + v1.w));
            sum += dppf<0xB1>(sum);
            sum += dppf<0x4E>(sum);
            sum += dppf<0x104>(sum);
            const float xr = __uint_as_float((unsigned)__builtin_amdgcn_ds_bpermute(
                4 * r, (int)__float_as_uint(xwin)));
            if (prod) {
                const int tt = (t2 & ~63) + r;
                out[(size_t)tt * BB + b] = sum + bo + xr;
            }
            xwin = xnext;
        }
    }
#undef LSTM_STEP
}

extern "C" void kernel_launch(void* const* d_in, const int* in_sizes, int n_in,
                              void* d_out, int out_size, void* d_ws, size_t ws_size,
                              hipStream_t stream) {
    (void)in_sizes; (void)n_in; (void)d_ws; (void)ws_size; (void)out_size;
    const float* x    = (const float*)d_in[0];
    const float* wih  = (const float*)d_in[1];
    const float* whh  = (const float*)d_in[2];
    const float* bih  = (const float*)d_in[3];
    const float* bhh  = (const float*)d_in[4];
    const float* wout = (const float*)d_in[5];
    const float* bout = (const float*)d_in[6];
    hipLaunchKernelGGL(lstm_fused, dim3(BB), dim3(512), 0, stream,
                       x, wih, whh, bih, bhh, wout, bout, (float*)d_out);
}